// Round 1
// baseline (113.045 us; speedup 1.0000x reference)
//
#include <hip/hip_runtime.h>

#define BATCH   16384
#define NKNOW   128
#define NEDGE   253
#define HIDDEN  256
#define RPB     16      // rows per block
#define APITCH  132     // padded pitch for sA/sB (breaks 16-way bank conflict)

__device__ __forceinline__ float sigm(float x) {
    return 1.0f / (1.0f + __expf(-x));
}

__global__ __launch_bounds__(256, 4) void fused_ncd(
    const int*   __restrict__ user_ids,
    const int*   __restrict__ item_ids,
    const float* __restrict__ item_know,
    const float* __restrict__ priori,
    const float* __restrict__ condi_p,
    const float* __restrict__ condi_n,
    const float* __restrict__ item_diff_w,
    const float* __restrict__ item_disc_w,
    const float* __restrict__ Wu,
    const float* __restrict__ bu,
    const float* __restrict__ Wi,
    const float* __restrict__ bi,
    float*       __restrict__ out)
{
    __shared__ float sPair[RPB][2 * NEDGE];   // (sqrt-)sigmoided condi pairs, interleaved
    __shared__ float sA[RPB][APITCH];         // know, then mastery*know
    __shared__ float sB[RPB][APITCH];         // sigmoid(diff)*know
    __shared__ float sRed[4][RPB];            // per-wave partial dot sums
    __shared__ float sDisc[RPB];

    const int tid  = threadIdx.x;
    const int lane = tid & 63;
    const int wid  = tid >> 6;
    const int r0   = blockIdx.x * RPB;

    // ---------------- Phase 1a: gather + sigmoid(+sqrt) into LDS ----------
    for (int rr = 0; rr < 4; ++rr) {
        const int r   = wid * 4 + rr;
        const int row = r0 + r;
        const int uid = user_ids[row];
        const float* cp = condi_p + (size_t)uid * NEDGE;
        const float* cn = condi_n + (size_t)uid * NEDGE;
        for (int e = lane; e < NEDGE; e += 64) {
            float p = sigm(cp[e]);
            float n = sigm(cn[e]);
            if (e >= 1) { p = sqrtf(p); n = sqrtf(n); }
            *(float2*)&sPair[r][2 * e] = make_float2(p, n);
        }
        const int iid = item_ids[row];
        const float* dw = item_diff_w + (size_t)iid * NKNOW;
        const float* kw = item_know   + (size_t)row * NKNOW;
        for (int e = lane; e < NKNOW; e += 64) {
            float kv = kw[e];
            sA[r][e] = kv;
            sB[r][e] = sigm(dw[e]) * kv;
        }
    }
    __syncthreads();

    // ---------------- Phase 1b: 16 serial posterior chains (1 lane each) --
    if (tid < RPB) {
        const int r   = tid;
        const int row = r0 + r;
        const int uid = user_ids[row];
        float p0  = sigm(priori[(size_t)uid * NKNOW]);        // only column 0 is used!
        float2 c0 = *(const float2*)&sPair[r][0];             // un-sqrted
        float p1  = c0.x * p0 + c0.y * (1.0f - p0);
        sA[r][0] *= p0;
        sA[r][1] *= p1;
        float pm2 = p0, pm1 = p1;
        for (int k = 2; k < NKNOW; ++k) {
            float2 a = *(const float2*)&sPair[r][2 * (125 + k)];  // cp_a/cn_a, sqrted
            float2 b = *(const float2*)&sPair[r][2 * (k - 1)];    // cp_b/cn_b, sqrted
            float ta = a.x * pm2 + a.y * (1.0f - pm2);
            float tb = b.x * pm1 + b.y * (1.0f - pm1);
            float pk = ta * tb;
            sA[r][k] *= pk;
            pm2 = pm1; pm1 = pk;
        }
        sDisc[r] = sigm(item_disc_w[item_ids[row]]);
    }
    __syncthreads();

    // ---------------- Phase 2: h = tid; two fused 128-dot GEMVs ----------
    float accU[RPB], accV[RPB];
    #pragma unroll
    for (int r = 0; r < RPB; ++r) { accU[r] = 0.0f; accV[r] = 0.0f; }

    const float4* WuR = (const float4*)(Wu + (size_t)tid * NKNOW);
    const float4* WiR = (const float4*)(Wi + (size_t)tid * NKNOW);

    for (int kc = 0; kc < NKNOW / 16; ++kc) {     // 8 chunks of 16 floats
        float4 wu[4], wi[4];
        #pragma unroll
        for (int j = 0; j < 4; ++j) { wu[j] = WuR[kc * 4 + j]; wi[j] = WiR[kc * 4 + j]; }
        #pragma unroll
        for (int r = 0; r < RPB; ++r) {
            const float4* ar = (const float4*)(&sA[r][0]) + kc * 4;
            const float4* br = (const float4*)(&sB[r][0]) + kc * 4;
            float au = accU[r], av = accV[r];
            #pragma unroll
            for (int j = 0; j < 4; ++j) {
                float4 a = ar[j];   // uniform address -> LDS broadcast, conflict-free
                au += wu[j].x * a.x + wu[j].y * a.y + wu[j].z * a.z + wu[j].w * a.w;
                float4 b = br[j];
                av += wi[j].x * b.x + wi[j].y * b.y + wi[j].z * b.z + wi[j].w * b.w;
            }
            accU[r] = au; accV[r] = av;
        }
    }

    const float bub = bu[tid], bib = bi[tid];
    #pragma unroll
    for (int r = 0; r < RPB; ++r) {
        float x = accU[r] + bub;
        float u = 1.0f - 2.0f / (1.0f + __expf(2.0f * x));    // tanh(x)
        float v = sigm(accV[r] + bib);
        float pr = u * v;
        #pragma unroll
        for (int off = 32; off > 0; off >>= 1)
            pr += __shfl_down(pr, off);
        if (lane == 0) sRed[wid][r] = pr;
    }
    __syncthreads();

    if (tid < RPB) {
        const int r = tid;
        float logit = sRed[0][r] + sRed[1][r] + sRed[2][r] + sRed[3][r] - sDisc[r];
        out[r0 + r] = sigm(logit);
    }
}

extern "C" void kernel_launch(void* const* d_in, const int* in_sizes, int n_in,
                              void* d_out, int out_size, void* d_ws, size_t ws_size,
                              hipStream_t stream) {
    const int*   user_ids    = (const int*)  d_in[0];
    const int*   item_ids    = (const int*)  d_in[1];
    const float* item_know   = (const float*)d_in[2];
    const float* priori      = (const float*)d_in[3];
    const float* condi_p     = (const float*)d_in[4];
    const float* condi_n     = (const float*)d_in[5];
    const float* item_diff_w = (const float*)d_in[6];
    const float* item_disc_w = (const float*)d_in[7];
    const float* Wu          = (const float*)d_in[8];
    const float* bu          = (const float*)d_in[9];
    const float* Wi          = (const float*)d_in[10];
    const float* bi          = (const float*)d_in[11];
    float* out = (float*)d_out;

    fused_ncd<<<BATCH / RPB, 256, 0, stream>>>(
        user_ids, item_ids, item_know, priori, condi_p, condi_n,
        item_diff_w, item_disc_w, Wu, bu, Wi, bi, out);
}

// Round 3
// 88.373 us; speedup vs baseline: 1.2792x; 1.2792x over previous
//
#include <hip/hip_runtime.h>

#define BATCH   16384
#define NKNOW   128
#define NEDGE   253
#define HIDDEN  256
#define RPB     16
#define PPITCH  508          // sPair row pitch (506 used + 2 pad)

typedef __attribute__((ext_vector_type(8))) short  s16x8;   // 8 bf16 (4 VGPRs) MFMA operand
typedef __attribute__((ext_vector_type(4))) float  f32x4;   // MFMA accumulator
typedef __attribute__((ext_vector_type(4))) int    i32x4;

typedef unsigned short ushort_t;
typedef unsigned int   uint_t;

__device__ __forceinline__ float sigm(float x) { return 1.0f / (1.0f + __expf(-x)); }

__device__ __forceinline__ ushort_t f2bf_rn(float x) {      // fp32 -> bf16 round-nearest-even
    uint_t u = __float_as_uint(x);
    u += 0x7FFFu + ((u >> 16) & 1u);
    return (ushort_t)(u >> 16);
}
__device__ __forceinline__ float bf2f(ushort_t h) { return __uint_as_float(((uint_t)h) << 16); }

// swizzled byte offset inside a [RPB][128]-ushort tile: row-major 256B rows,
// XOR bits 4-6 with row&7 -> 16B slots spread over 8 bank-groups (2-way = free)
__device__ __forceinline__ int swz(int row, int kbyte) {
    return row * 256 + (kbyte ^ ((row & 7) << 4));
}

__device__ __forceinline__ void store_pair(char* Mh, char* Ml, int r, int k0, float va, float vb) {
    int off = swz(r, k0 * 2);                       // k0 even -> 4B aligned
    ushort_t ha = f2bf_rn(va); ushort_t la = f2bf_rn(va - bf2f(ha));
    ushort_t hb = f2bf_rn(vb); ushort_t lb = f2bf_rn(vb - bf2f(hb));
    *(uint_t*)(Mh + off) = (uint_t)ha | ((uint_t)hb << 16);
    *(uint_t*)(Ml + off) = (uint_t)la | ((uint_t)lb << 16);
}

// ---- pre-kernel: Wu/Wi fp32 [256][128] -> bf16 hi/lo blocks in d_ws --------
__global__ void conv_w(const float* __restrict__ Wu, const float* __restrict__ Wi,
                       ushort_t* __restrict__ wsp) {
    int i = blockIdx.x * 256 + threadIdx.x;         // 0..65535
    bool isU = i < 32768;
    int  j   = isU ? i : i - 32768;
    float w  = isU ? Wu[j] : Wi[j];
    ushort_t h = f2bf_rn(w);
    ushort_t l = f2bf_rn(w - bf2f(h));
    int base = isU ? 0 : 65536;
    wsp[base + j]         = h;                      // hi block
    wsp[base + 32768 + j] = l;                      // lo block
}

__global__ __launch_bounds__(256, 3) void fused_ncd(
    const int*   __restrict__ user_ids,
    const int*   __restrict__ item_ids,
    const float* __restrict__ item_know,
    const float* __restrict__ priori,
    const float* __restrict__ condi_p,
    const float* __restrict__ condi_n,
    const float* __restrict__ item_diff_w,
    const float* __restrict__ item_disc_w,
    const float* __restrict__ bu,
    const float* __restrict__ bi,
    const ushort_t* __restrict__ wsp,
    float*       __restrict__ out)
{
    __shared__ float    sPair[RPB][PPITCH];             // sigmoided condi pairs (fp32!)
    __shared__ __align__(16) ushort_t sMhi[RPB * 128];  // mastery hi (bf16, swizzled)
    __shared__ __align__(16) ushort_t sMlo[RPB * 128];  // mastery lo residual
    __shared__ __align__(16) ushort_t sDhi[RPB * 128];  // sigmoid(diff)*know hi
    __shared__ __align__(16) ushort_t sDlo[RPB * 128];  // sigmoid(diff)*know lo
    __shared__ __align__(16) ushort_t sKm [RPB * 128];  // know mask 0xFFFF/0
    __shared__ float sRed[4][RPB];
    __shared__ float sDisc[RPB];

    const int tid  = threadIdx.x;
    const int lane = tid & 63;
    const int wid  = tid >> 6;
    const int r0   = blockIdx.x * RPB;

    // ---------------- Phase 1a: gathers + sigmoid into LDS ----------------
    for (int rr = 0; rr < 4; ++rr) {
        const int r   = wid * 4 + rr;
        const int row = r0 + r;
        const int uid = user_ids[row];
        const int iid = item_ids[row];
        const float* cp = condi_p + (size_t)uid * NEDGE;
        const float* cn = condi_n + (size_t)uid * NEDGE;
        for (int e = lane; e < NEDGE; e += 64) {
            float p = sigm(cp[e]);
            float n = sigm(cn[e]);
            if (e >= 1) { p = sqrtf(p); n = sqrtf(n); }
            *(float2*)&sPair[r][2 * e] = make_float2(p, n);
        }
        const float* dw = item_diff_w + (size_t)iid * NKNOW;
        const float* kw = item_know   + (size_t)row * NKNOW;
        for (int e = lane; e < NKNOW; e += 64) {
            float kv = kw[e];
            float dv = sigm(dw[e]) * kv;            // know in {0,1} -> exact
            ushort_t dh = f2bf_rn(dv);
            ushort_t dl = f2bf_rn(dv - bf2f(dh));
            int off = swz(r, 2 * e);
            *(ushort_t*)((char*)sDhi + off) = dh;
            *(ushort_t*)((char*)sDlo + off) = dl;
            *(ushort_t*)((char*)sKm  + off) = (kv > 0.5f) ? (ushort_t)0xFFFFu : (ushort_t)0;
        }
    }
    __syncthreads();

    // ---------------- Phase 1b: 16 serial posterior chains ----------------
    if (tid < RPB) {
        const int r   = tid;
        const int row = r0 + r;
        const int uid = user_ids[row];
        const int iid = item_ids[row];
        const float* P = &sPair[r][0];
        float p0 = sigm(priori[(size_t)uid * NKNOW]);       // only column 0 used
        float2 c0 = *(const float2*)&P[0];                  // un-sqrted
        float p1 = c0.x * p0 + c0.y * (1.0f - p0);
        store_pair((char*)sMhi, (char*)sMlo, r, 0, p0, p1);
        float pm2 = p0, pm1 = p1, pev = 0.0f;
        for (int k = 2; k < NKNOW; ++k) {
            float2 a = *(const float2*)&P[2 * (125 + k)];   // cp_a/cn_a (sqrted)
            float2 b = *(const float2*)&P[2 * (k - 1)];     // cp_b/cn_b (sqrted)
            float ta = fmaf(pm2, a.x - a.y, a.y);
            float tb = fmaf(pm1, b.x - b.y, b.y);
            float pk = ta * tb;
            if (k & 1) store_pair((char*)sMhi, (char*)sMlo, r, k - 1, pev, pk);
            else       pev = pk;
            pm2 = pm1; pm1 = pk;
        }
        sDisc[r] = sigm(item_disc_w[iid]);
    }
    __syncthreads();

    // ---------------- Phase 2: MFMA bf16x3 (hi/lo) --------------------------
    // wave w owns hidden cols [w*64, w*64+64); A rows = the 16 batch rows.
    const int l15 = lane & 15, lq = lane >> 4;
    const ushort_t* WuH = wsp;
    const ushort_t* WuL = wsp + 32768;
    const ushort_t* WiH = wsp + 65536;
    const ushort_t* WiL = wsp + 98304;

    float rowsum[4] = {0.f, 0.f, 0.f, 0.f};

    for (int t = 0; t < 4; ++t) {
        const int hcol = wid * 64 + t * 16 + l15;
        f32x4 accU = {0.f, 0.f, 0.f, 0.f};
        f32x4 accV = {0.f, 0.f, 0.f, 0.f};
        const ushort_t* wuh = WuH + hcol * NKNOW;
        const ushort_t* wul = WuL + hcol * NKNOW;
        const ushort_t* wih = WiH + hcol * NKNOW;
        const ushort_t* wil = WiL + hcol * NKNOW;
        #pragma unroll
        for (int kc = 0; kc < 4; ++kc) {
            const int offA = swz(l15, kc * 64 + lq * 16);   // 16B fragment, swizzled
            const int ke   = kc * 32 + lq * 8;              // element offset in W row
            i32x4 km = *(const i32x4*)((const char*)sKm  + offA);
            i32x4 mh = *(const i32x4*)((const char*)sMhi + offA) & km;  // exact mask
            i32x4 ml = *(const i32x4*)((const char*)sMlo + offA) & km;
            s16x8 ah = *(s16x8*)&mh;
            s16x8 al = *(s16x8*)&ml;
            s16x8 bh = *(const s16x8*)((const char*)sDhi + offA);
            s16x8 bl = *(const s16x8*)((const char*)sDlo + offA);
            s16x8 uh = *(const s16x8*)(wuh + ke);
            s16x8 ul = *(const s16x8*)(wul + ke);
            s16x8 ih = *(const s16x8*)(wih + ke);
            s16x8 il = *(const s16x8*)(wil + ke);
            accU = __builtin_amdgcn_mfma_f32_16x16x32_bf16(ah, uh, accU, 0, 0, 0);
            accU = __builtin_amdgcn_mfma_f32_16x16x32_bf16(ah, ul, accU, 0, 0, 0);
            accU = __builtin_amdgcn_mfma_f32_16x16x32_bf16(al, uh, accU, 0, 0, 0);
            accV = __builtin_amdgcn_mfma_f32_16x16x32_bf16(bh, ih, accV, 0, 0, 0);
            accV = __builtin_amdgcn_mfma_f32_16x16x32_bf16(bh, il, accV, 0, 0, 0);
            accV = __builtin_amdgcn_mfma_f32_16x16x32_bf16(bl, ih, accV, 0, 0, 0);
        }
        const float bub = bu[hcol], bib = bi[hcol];
        #pragma unroll
        for (int j = 0; j < 4; ++j) {                        // C/D: col=l&15, row=lq*4+j
            float x = accU[j] + bub;
            float u = 1.0f - 2.0f / (1.0f + __expf(2.0f * x));   // tanh
            float v = sigm(accV[j] + bib);
            rowsum[j] += u * v;
        }
    }

    #pragma unroll
    for (int j = 0; j < 4; ++j) {
        float v = rowsum[j];
        v += __shfl_xor(v, 1);
        v += __shfl_xor(v, 2);
        v += __shfl_xor(v, 4);
        v += __shfl_xor(v, 8);
        if (l15 == 0) sRed[wid][lq * 4 + j] = v;
    }
    __syncthreads();

    if (tid < RPB) {
        float logit = sRed[0][tid] + sRed[1][tid] + sRed[2][tid] + sRed[3][tid] - sDisc[tid];
        out[r0 + tid] = sigm(logit);
    }
}

extern "C" void kernel_launch(void* const* d_in, const int* in_sizes, int n_in,
                              void* d_out, int out_size, void* d_ws, size_t ws_size,
                              hipStream_t stream) {
    const int*   user_ids    = (const int*)  d_in[0];
    const int*   item_ids    = (const int*)  d_in[1];
    const float* item_know   = (const float*)d_in[2];
    const float* priori      = (const float*)d_in[3];
    const float* condi_p     = (const float*)d_in[4];
    const float* condi_n     = (const float*)d_in[5];
    const float* item_diff_w = (const float*)d_in[6];
    const float* item_disc_w = (const float*)d_in[7];
    const float* Wu          = (const float*)d_in[8];
    const float* bu          = (const float*)d_in[9];
    const float* Wi          = (const float*)d_in[10];
    const float* bi          = (const float*)d_in[11];
    float* out = (float*)d_out;
    ushort_t* wsp = (ushort_t*)d_ws;                 // needs 256 KiB

    conv_w<<<256, 256, 0, stream>>>(Wu, Wi, wsp);
    fused_ncd<<<BATCH / RPB, 256, 0, stream>>>(
        user_ids, item_ids, item_know, priori, condi_p, condi_n,
        item_diff_w, item_disc_w, bu, bi, wsp, out);
}

// Round 5
// 76.268 us; speedup vs baseline: 1.4822x; 1.1587x over previous
//
#include <hip/hip_runtime.h>

#define BATCH   16384
#define NKNOW   128
#define NEDGE   253
#define HIDDEN  256
#define RPB     16
#define PPITCH  522          // sPair pitch: 522 mod 32 = 10 -> 16 chain lanes spread banks; room for prefetch overread (<=513)
#define RPB3    32           // rows per block in gemm kernel

typedef __attribute__((ext_vector_type(8))) short  s16x8;   // 8 bf16 (4 VGPRs) MFMA operand
typedef __attribute__((ext_vector_type(4))) float  f32x4;   // MFMA accumulator
typedef __attribute__((ext_vector_type(4))) int    i32x4;

typedef unsigned short ushort_t;
typedef unsigned int   uint_t;

__device__ __forceinline__ float sigm(float x) { return 1.0f / (1.0f + __expf(-x)); }

__device__ __forceinline__ ushort_t f2bf_rn(float x) {      // fp32 -> bf16 round-nearest-even
    uint_t u = __float_as_uint(x);
    u += 0x7FFFu + ((u >> 16) & 1u);
    return (ushort_t)(u >> 16);
}
__device__ __forceinline__ float bf2f(ushort_t h) { return __uint_as_float(((uint_t)h) << 16); }

// ---- pre-kernel: Wu/Wi fp32 [256][128] -> bf16 hi/lo blocks in d_ws --------
__global__ void conv_w(const float* __restrict__ Wu, const float* __restrict__ Wi,
                       ushort_t* __restrict__ wsp) {
    int i = blockIdx.x * 256 + threadIdx.x;         // 0..65535
    bool isU = i < 32768;
    int  j   = isU ? i : i - 32768;
    float w  = isU ? Wu[j] : Wi[j];
    ushort_t h = f2bf_rn(w);
    ushort_t l = f2bf_rn(w - bf2f(h));
    int base = isU ? 0 : 65536;
    wsp[base + j]         = h;                      // hi block
    wsp[base + 32768 + j] = l;                      // lo block
}

// ======================= Kernel A: prep (phase 1) ==========================
// Gathers + sigmoids + 16 serial posterior chains; writes masked mastery
// hi/lo (bf16 pairs packed in uint) and D=sigm(diff)*know hi/lo to d_ws.
__global__ __launch_bounds__(256, 3) void prep_ncd(
    const int*   __restrict__ user_ids,
    const int*   __restrict__ item_ids,
    const float* __restrict__ item_know,
    const float* __restrict__ priori,
    const float* __restrict__ condi_p,
    const float* __restrict__ condi_n,
    const float* __restrict__ item_diff_w,
    uint_t*      __restrict__ mhi32,     // [BATCH][64] uints (= [BATCH][128] bf16)
    uint_t*      __restrict__ mlo32,
    ushort_t*    __restrict__ dhi,       // [BATCH][128] bf16
    ushort_t*    __restrict__ dlo)
{
    __shared__ float    sPair[RPB][PPITCH];     // sigmoided condi pairs (fp32)
    __shared__ uint_t   sMh32[RPB * 64];        // mastery hi pairs, XOR-swizzled
    __shared__ uint_t   sMl32[RPB * 64];
    __shared__ ushort_t sKm[RPB * 128];         // know mask 0xFFFF/0, XOR-swizzled

    const int tid  = threadIdx.x;
    const int lane = tid & 63;
    const int wid  = tid >> 6;
    const int r0   = blockIdx.x * RPB;

    // ---------------- Phase 1a: gathers + sigmoid ----------------
    for (int rr = 0; rr < 4; ++rr) {
        const int r   = wid * 4 + rr;
        const int row = r0 + r;
        const int uid = user_ids[row];
        const int iid = item_ids[row];
        const float* cp = condi_p + (size_t)uid * NEDGE;
        const float* cn = condi_n + (size_t)uid * NEDGE;
        for (int e = lane; e < NEDGE; e += 64) {
            float p = sigm(cp[e]);
            float n = sigm(cn[e]);
            if (e >= 1) { p = sqrtf(p); n = sqrtf(n); }
            *(float2*)&sPair[r][2 * e] = make_float2(p, n);
        }
        const float* dw = item_diff_w + (size_t)iid * NKNOW;
        const float* kw = item_know   + (size_t)row * NKNOW;
        for (int e = lane; e < NKNOW; e += 64) {
            float kv = kw[e];
            float dv = sigm(dw[e]) * kv;                        // know in {0,1} -> exact
            ushort_t dh = f2bf_rn(dv);
            ushort_t dl = f2bf_rn(dv - bf2f(dh));
            dhi[(size_t)row * NKNOW + e] = dh;                  // coalesced 2B stores
            dlo[(size_t)row * NKNOW + e] = dl;
            *(ushort_t*)((char*)sKm + r * 256 + ((2 * e) ^ ((r & 7) << 4))) =
                (kv > 0.5f) ? (ushort_t)0xFFFFu : (ushort_t)0;
        }
    }
    __syncthreads();

    // ---------------- Phase 1b: serial chains, depth-4 LDS prefetch -------
    if (tid < RPB) {
        const int r   = tid;
        const int row = r0 + r;
        const int uid = user_ids[row];
        const float* P = &sPair[r][0];
#define PA(k) (*(const float2*)&P[2 * (125 + (k))])
#define PB(k) (*(const float2*)&P[2 * ((k) - 1)])
        float p0 = sigm(priori[(size_t)uid * NKNOW]);           // only column 0 used
        float2 c0 = *(const float2*)&P[0];                      // un-sqrted pair
        float p1 = c0.x * p0 + c0.y * (1.0f - p0);

        auto store_masked = [&](int k0, float va, float vb) {   // k0 even
            int off = r * 256 + ((2 * k0) ^ ((r & 7) << 4));
            uint_t km = *(const uint_t*)((const char*)sKm + off);
            ushort_t ha = f2bf_rn(va), la = f2bf_rn(va - bf2f(ha));
            ushort_t hb = f2bf_rn(vb), lb = f2bf_rn(vb - bf2f(hb));
            *(uint_t*)((char*)sMh32 + off) = ((uint_t)ha | ((uint_t)hb << 16)) & km;
            *(uint_t*)((char*)sMl32 + off) = ((uint_t)la | ((uint_t)lb << 16)) & km;
        };
        store_masked(0, p0, p1);

        float pm2 = p0, pm1 = p1;
        float2 c0a = PA(2), c0b = PB(2), c1a = PA(3), c1b = PB(3);
        float2 n0a = PA(4), n0b = PB(4), n1a = PA(5), n1b = PB(5);
        for (int k = 2; k < NKNOW; k += 2) {
            // prefetch chunk k+4/k+5 (pad: max read P[513] < 522)
            float2 q0a = PA(k + 4), q0b = PB(k + 4);
            float2 q1a = PA(k + 5), q1b = PB(k + 5);
            float ta  = fmaf(pm2, c0a.x - c0a.y, c0a.y);
            float tb  = fmaf(pm1, c0b.x - c0b.y, c0b.y);
            float pk  = ta * tb;                                 // p_k
            float ta2 = fmaf(pm1, c1a.x - c1a.y, c1a.y);
            float tb2 = fmaf(pk,  c1b.x - c1b.y, c1b.y);
            float pk2 = ta2 * tb2;                               // p_{k+1}
            store_masked(k, pk, pk2);
            pm2 = pk; pm1 = pk2;
            c0a = n0a; c0b = n0b; c1a = n1a; c1b = n1b;
            n0a = q0a; n0b = q0b; n1a = q1a; n1b = q1b;
        }
#undef PA
#undef PB
    }
    __syncthreads();

    // ---------------- copy-out: LDS (swizzled) -> global (linear) ---------
    for (int idx = tid; idx < RPB * 64; idx += 256) {
        const int r = idx >> 6, c = idx & 63;
        const int off = r * 256 + ((c * 4) ^ ((r & 7) << 4));
        mhi32[(size_t)r0 * 64 + idx] = *(const uint_t*)((const char*)sMh32 + off);
        mlo32[(size_t)r0 * 64 + idx] = *(const uint_t*)((const char*)sMl32 + off);
    }
}

// ======================= Kernel B: gemm (phase 2) ==========================
// 512 blocks x 32 rows; wave w owns hidden cols [w*64, w*64+64).
__global__ __launch_bounds__(256, 2) void gemm_ncd(
    const int*   __restrict__ item_ids,
    const float* __restrict__ item_disc_w,
    const float* __restrict__ bu,
    const float* __restrict__ bi,
    const ushort_t* __restrict__ wsp,    // W bf16 hi/lo blocks
    const uint_t*   __restrict__ mhi32,
    const uint_t*   __restrict__ mlo32,
    const uint_t*   __restrict__ dhi32,
    const uint_t*   __restrict__ dlo32,
    float*       __restrict__ out)
{
    __shared__ float sRed[4][RPB3];

    const int tid  = threadIdx.x;
    const int lane = tid & 63;
    const int wid  = tid >> 6;
    const int l15  = lane & 15, lq = lane >> 4;
    const int r0   = blockIdx.x * RPB3;

    const ushort_t* WuH = wsp;
    const ushort_t* WuL = wsp + 32768;
    const ushort_t* WiH = wsp + 65536;
    const ushort_t* WiL = wsp + 98304;

    float rowsum[2][4] = {{0.f,0.f,0.f,0.f},{0.f,0.f,0.f,0.f}};

    #pragma unroll 1
    for (int t = 0; t < 4; ++t) {
        const int hcol = wid * 64 + t * 16 + l15;
        s16x8 uh[4], ul[4], ih[4], il[4];
        #pragma unroll
        for (int kc = 0; kc < 4; ++kc) {
            const int ke = kc * 32 + lq * 8;
            uh[kc] = *(const s16x8*)(WuH + hcol * NKNOW + ke);
            ul[kc] = *(const s16x8*)(WuL + hcol * NKNOW + ke);
            ih[kc] = *(const s16x8*)(WiH + hcol * NKNOW + ke);
            il[kc] = *(const s16x8*)(WiL + hcol * NKNOW + ke);
        }
        const float bub = bu[hcol], bib = bi[hcol];

        #pragma unroll
        for (int rg = 0; rg < 2; ++rg) {
            const int row = r0 + rg * 16 + l15;
            f32x4 accU = {0.f, 0.f, 0.f, 0.f};
            f32x4 accV = {0.f, 0.f, 0.f, 0.f};
            #pragma unroll
            for (int kc = 0; kc < 4; ++kc) {
                const int aoff = row * 64 + kc * 16 + lq * 4;     // uint index
                s16x8 mh = *(const s16x8*)(mhi32 + aoff);
                s16x8 ml = *(const s16x8*)(mlo32 + aoff);
                s16x8 dh = *(const s16x8*)(dhi32 + aoff);
                s16x8 dl = *(const s16x8*)(dlo32 + aoff);
                accU = __builtin_amdgcn_mfma_f32_16x16x32_bf16(mh, uh[kc], accU, 0, 0, 0);
                accU = __builtin_amdgcn_mfma_f32_16x16x32_bf16(mh, ul[kc], accU, 0, 0, 0);
                accU = __builtin_amdgcn_mfma_f32_16x16x32_bf16(ml, uh[kc], accU, 0, 0, 0);
                accV = __builtin_amdgcn_mfma_f32_16x16x32_bf16(dh, ih[kc], accV, 0, 0, 0);
                accV = __builtin_amdgcn_mfma_f32_16x16x32_bf16(dh, il[kc], accV, 0, 0, 0);
                accV = __builtin_amdgcn_mfma_f32_16x16x32_bf16(dl, ih[kc], accV, 0, 0, 0);
            }
            #pragma unroll
            for (int j = 0; j < 4; ++j) {                 // C/D: col=l15, row=lq*4+j
                float x = accU[j] + bub;
                float u = 1.0f - 2.0f / (1.0f + __expf(2.0f * x));   // tanh
                float v = sigm(accV[j] + bib);
                rowsum[rg][j] += u * v;
            }
        }
    }

    #pragma unroll
    for (int rg = 0; rg < 2; ++rg)
        #pragma unroll
        for (int j = 0; j < 4; ++j) {
            float v = rowsum[rg][j];
            v += __shfl_xor(v, 1);
            v += __shfl_xor(v, 2);
            v += __shfl_xor(v, 4);
            v += __shfl_xor(v, 8);
            if (l15 == 0) sRed[wid][rg * 16 + lq * 4 + j] = v;
        }
    __syncthreads();

    if (tid < RPB3) {
        const int row = r0 + tid;
        float s = sRed[0][tid] + sRed[1][tid] + sRed[2][tid] + sRed[3][tid];
        float disc = sigm(item_disc_w[item_ids[row]]);
        out[row] = sigm(s - disc);
    }
}

// ======================= Fallback: R1 fused kernel =========================
#define APITCH  132
__device__ __forceinline__ int swz(int row, int kbyte) {
    return row * 256 + (kbyte ^ ((row & 7) << 4));
}
__device__ __forceinline__ void store_pair(char* Mh, char* Ml, int r, int k0, float va, float vb) {
    int off = swz(r, k0 * 2);
    ushort_t ha = f2bf_rn(va); ushort_t la = f2bf_rn(va - bf2f(ha));
    ushort_t hb = f2bf_rn(vb); ushort_t lb = f2bf_rn(vb - bf2f(hb));
    *(uint_t*)(Mh + off) = (uint_t)ha | ((uint_t)hb << 16);
    *(uint_t*)(Ml + off) = (uint_t)la | ((uint_t)lb << 16);
}

__global__ __launch_bounds__(256, 3) void fused_ncd(
    const int*   __restrict__ user_ids,
    const int*   __restrict__ item_ids,
    const float* __restrict__ item_know,
    const float* __restrict__ priori,
    const float* __restrict__ condi_p,
    const float* __restrict__ condi_n,
    const float* __restrict__ item_diff_w,
    const float* __restrict__ item_disc_w,
    const float* __restrict__ bu,
    const float* __restrict__ bi,
    const ushort_t* __restrict__ wsp,
    float*       __restrict__ out)
{
    __shared__ float    sPair[RPB][508];
    __shared__ __align__(16) ushort_t sMhi[RPB * 128];
    __shared__ __align__(16) ushort_t sMlo[RPB * 128];
    __shared__ __align__(16) ushort_t sDhi[RPB * 128];
    __shared__ __align__(16) ushort_t sDlo[RPB * 128];
    __shared__ __align__(16) ushort_t sKmF[RPB * 128];
    __shared__ float sRed[4][RPB];
    __shared__ float sDisc[RPB];

    const int tid  = threadIdx.x;
    const int lane = tid & 63;
    const int wid  = tid >> 6;
    const int r0   = blockIdx.x * RPB;

    for (int rr = 0; rr < 4; ++rr) {
        const int r   = wid * 4 + rr;
        const int row = r0 + r;
        const int uid = user_ids[row];
        const int iid = item_ids[row];
        const float* cp = condi_p + (size_t)uid * NEDGE;
        const float* cn = condi_n + (size_t)uid * NEDGE;
        for (int e = lane; e < NEDGE; e += 64) {
            float p = sigm(cp[e]);
            float n = sigm(cn[e]);
            if (e >= 1) { p = sqrtf(p); n = sqrtf(n); }
            *(float2*)&sPair[r][2 * e] = make_float2(p, n);
        }
        const float* dw = item_diff_w + (size_t)iid * NKNOW;
        const float* kw = item_know   + (size_t)row * NKNOW;
        for (int e = lane; e < NKNOW; e += 64) {
            float kv = kw[e];
            float dv = sigm(dw[e]) * kv;
            ushort_t dh = f2bf_rn(dv);
            ushort_t dl = f2bf_rn(dv - bf2f(dh));
            int off = swz(r, 2 * e);
            *(ushort_t*)((char*)sDhi + off) = dh;
            *(ushort_t*)((char*)sDlo + off) = dl;
            *(ushort_t*)((char*)sKmF + off) = (kv > 0.5f) ? (ushort_t)0xFFFFu : (ushort_t)0;
        }
    }
    __syncthreads();

    if (tid < RPB) {
        const int r   = tid;
        const int row = r0 + r;
        const int uid = user_ids[row];
        const int iid = item_ids[row];
        const float* P = &sPair[r][0];
        float p0 = sigm(priori[(size_t)uid * NKNOW]);
        float2 c0 = *(const float2*)&P[0];
        float p1 = c0.x * p0 + c0.y * (1.0f - p0);
        store_pair((char*)sMhi, (char*)sMlo, r, 0, p0, p1);
        float pm2 = p0, pm1 = p1, pev = 0.0f;
        for (int k = 2; k < NKNOW; ++k) {
            float2 a = *(const float2*)&P[2 * (125 + k)];
            float2 b = *(const float2*)&P[2 * (k - 1)];
            float ta = fmaf(pm2, a.x - a.y, a.y);
            float tb = fmaf(pm1, b.x - b.y, b.y);
            float pk = ta * tb;
            if (k & 1) store_pair((char*)sMhi, (char*)sMlo, r, k - 1, pev, pk);
            else       pev = pk;
            pm2 = pm1; pm1 = pk;
        }
        sDisc[r] = sigm(item_disc_w[iid]);
    }
    __syncthreads();

    const int l15 = lane & 15, lq = lane >> 4;
    const ushort_t* WuH = wsp;
    const ushort_t* WuL = wsp + 32768;
    const ushort_t* WiH = wsp + 65536;
    const ushort_t* WiL = wsp + 98304;

    float rowsum[4] = {0.f, 0.f, 0.f, 0.f};

    for (int t = 0; t < 4; ++t) {
        const int hcol = wid * 64 + t * 16 + l15;
        f32x4 accU = {0.f, 0.f, 0.f, 0.f};
        f32x4 accV = {0.f, 0.f, 0.f, 0.f};
        const ushort_t* wuh = WuH + hcol * NKNOW;
        const ushort_t* wul = WuL + hcol * NKNOW;
        const ushort_t* wih = WiH + hcol * NKNOW;
        const ushort_t* wil = WiL + hcol * NKNOW;
        #pragma unroll
        for (int kc = 0; kc < 4; ++kc) {
            const int offA = swz(l15, kc * 64 + lq * 16);
            const int ke   = kc * 32 + lq * 8;
            i32x4 km = *(const i32x4*)((const char*)sKmF + offA);
            i32x4 mh = *(const i32x4*)((const char*)sMhi + offA) & km;
            i32x4 ml = *(const i32x4*)((const char*)sMlo + offA) & km;
            s16x8 ah = *(s16x8*)&mh;
            s16x8 al = *(s16x8*)&ml;
            s16x8 bh = *(const s16x8*)((const char*)sDhi + offA);
            s16x8 bl = *(const s16x8*)((const char*)sDlo + offA);
            s16x8 uh = *(const s16x8*)(wuh + ke);
            s16x8 ul = *(const s16x8*)(wul + ke);
            s16x8 ih = *(const s16x8*)(wih + ke);
            s16x8 il = *(const s16x8*)(wil + ke);
            accU = __builtin_amdgcn_mfma_f32_16x16x32_bf16(ah, uh, accU, 0, 0, 0);
            accU = __builtin_amdgcn_mfma_f32_16x16x32_bf16(ah, ul, accU, 0, 0, 0);
            accU = __builtin_amdgcn_mfma_f32_16x16x32_bf16(al, uh, accU, 0, 0, 0);
            accV = __builtin_amdgcn_mfma_f32_16x16x32_bf16(bh, ih, accV, 0, 0, 0);
            accV = __builtin_amdgcn_mfma_f32_16x16x32_bf16(bh, il, accV, 0, 0, 0);
            accV = __builtin_amdgcn_mfma_f32_16x16x32_bf16(bl, ih, accV, 0, 0, 0);
        }
        const float bub = bu[hcol], bib = bi[hcol];
        #pragma unroll
        for (int j = 0; j < 4; ++j) {
            float x = accU[j] + bub;
            float u = 1.0f - 2.0f / (1.0f + __expf(2.0f * x));
            float v = sigm(accV[j] + bib);
            rowsum[j] += u * v;
        }
    }

    #pragma unroll
    for (int j = 0; j < 4; ++j) {
        float v = rowsum[j];
        v += __shfl_xor(v, 1);
        v += __shfl_xor(v, 2);
        v += __shfl_xor(v, 4);
        v += __shfl_xor(v, 8);
        if (l15 == 0) sRed[wid][lq * 4 + j] = v;
    }
    __syncthreads();

    if (tid < RPB) {
        float logit = sRed[0][tid] + sRed[1][tid] + sRed[2][tid] + sRed[3][tid] - sDisc[tid];
        out[r0 + tid] = sigm(logit);
    }
}

extern "C" void kernel_launch(void* const* d_in, const int* in_sizes, int n_in,
                              void* d_out, int out_size, void* d_ws, size_t ws_size,
                              hipStream_t stream) {
    const int*   user_ids    = (const int*)  d_in[0];
    const int*   item_ids    = (const int*)  d_in[1];
    const float* item_know   = (const float*)d_in[2];
    const float* priori      = (const float*)d_in[3];
    const float* condi_p     = (const float*)d_in[4];
    const float* condi_n     = (const float*)d_in[5];
    const float* item_diff_w = (const float*)d_in[6];
    const float* item_disc_w = (const float*)d_in[7];
    const float* Wu          = (const float*)d_in[8];
    const float* bu          = (const float*)d_in[9];
    const float* Wi          = (const float*)d_in[10];
    const float* bi          = (const float*)d_in[11];
    float* out = (float*)d_out;

    char* base = (char*)d_ws;
    ushort_t* wsp = (ushort_t*)base;                         // 256 KiB
    const size_t MB4 = (size_t)4 << 20;
    uint_t*   mhi32 = (uint_t*)(base + (1 << 18));
    uint_t*   mlo32 = (uint_t*)(base + (1 << 18) + MB4);
    ushort_t* dhi   = (ushort_t*)(base + (1 << 18) + 2 * MB4);
    ushort_t* dlo   = (ushort_t*)(base + (1 << 18) + 3 * MB4);
    const size_t need = (1 << 18) + 4 * MB4;                 // ~17 MiB

    conv_w<<<256, 256, 0, stream>>>(Wu, Wi, wsp);

    if (ws_size >= need) {
        prep_ncd<<<BATCH / RPB, 256, 0, stream>>>(
            user_ids, item_ids, item_know, priori, condi_p, condi_n,
            item_diff_w, mhi32, mlo32, dhi, dlo);
        gemm_ncd<<<BATCH / RPB3, 256, 0, stream>>>(
            item_ids, item_disc_w, bu, bi, wsp,
            mhi32, mlo32, (const uint_t*)dhi, (const uint_t*)dlo, out);
    } else {
        fused_ncd<<<BATCH / RPB, 256, 0, stream>>>(
            user_ids, item_ids, item_know, priori, condi_p, condi_n,
            item_diff_w, item_disc_w, bu, bi, wsp, out);
    }
}

// Round 7
// 65.568 us; speedup vs baseline: 1.7241x; 1.1632x over previous
//
#include <hip/hip_runtime.h>

#define BATCH   16384
#define NKNOW   128
#define NEDGE   253
#define RPB     16
#define RPB3    32

typedef __attribute__((ext_vector_type(8))) short  s16x8;   // 8 bf16 MFMA operand
typedef __attribute__((ext_vector_type(4))) float  f32x4;   // MFMA accumulator
typedef __attribute__((ext_vector_type(4))) int    i32x4;

typedef unsigned short u16;
typedef unsigned int   u32;
typedef unsigned long long u64;

__device__ __forceinline__ float sigm(float x) { return 1.0f / (1.0f + __expf(-x)); }

__device__ __forceinline__ u16 f2bf_rn(float x) {
    u32 u = __float_as_uint(x);
    u += 0x7FFFu + ((u >> 16) & 1u);
    return (u16)(u >> 16);
}
__device__ __forceinline__ float bf2f(u16 h) { return __uint_as_float(((u32)h) << 16); }

// ---- pre-kernel: Wu/Wi fp32 [256][128] -> bf16 hi/lo blocks in d_ws --------
__global__ void conv_w(const float* __restrict__ Wu, const float* __restrict__ Wi,
                       u16* __restrict__ wsp) {
    int i = blockIdx.x * 256 + threadIdx.x;
    bool isU = i < 32768;
    int  j   = isU ? i : i - 32768;
    float w  = isU ? Wu[j] : Wi[j];
    u16 h = f2bf_rn(w);
    u16 l = f2bf_rn(w - bf2f(h));
    int base = isU ? 0 : 65536;
    wsp[base + j]         = h;
    wsp[base + 32768 + j] = l;
}

// ======================= K1: gather (wave-per-row, no LDS) =================
// chainbuf[row][0]      = header (sig cp0, sig cn0, sig priori0, 0)
// chainbuf[row][1..126] = step k=slot+1: (cpa,cna,cpb,cnb) sqrt'd sigmoids
// chainbuf[row][127]    = know bitmask (4x u32)
__global__ __launch_bounds__(256, 4) void gather_ncd(
    const int*   __restrict__ user_ids,
    const int*   __restrict__ item_ids,
    const float* __restrict__ item_know,
    const float* __restrict__ priori,
    const float* __restrict__ condi_p,
    const float* __restrict__ condi_n,
    const float* __restrict__ item_diff_w,
    float4*      __restrict__ chainbuf,
    u16*         __restrict__ dhi,
    u16*         __restrict__ dlo)
{
    const int wid = threadIdx.x >> 6, j = threadIdx.x & 63;
    const int row = blockIdx.x * 4 + wid;
    const int uid = user_ids[row], iid = item_ids[row];
    const float* cp = condi_p + (size_t)uid * NEDGE;
    const float* cn = condi_n + (size_t)uid * NEDGE;
    const float* kw = item_know   + (size_t)row * NKNOW;
    const float* dw = item_diff_w + (size_t)iid * NKNOW;

    // issue all independent loads up front
    float a0p = cp[127 + j], a0n = cn[127 + j], b0p = cp[1 + j], b0n = cn[1 + j];
    float a1p = 0.f, a1n = 0.f, b1p = 0.f, b1n = 0.f;
    if (j < 62) { a1p = cp[191 + j]; a1n = cn[191 + j]; b1p = cp[65 + j]; b1n = cn[65 + j]; }
    float k0 = kw[j], k1 = kw[64 + j];
    float d0 = dw[j], d1 = dw[64 + j];
    float c0p = cp[0], c0n = cn[0], pri = priori[(size_t)uid * NKNOW];

    float4* cb = chainbuf + (size_t)row * 128;
    float4 sA;
    sA.x = sqrtf(sigm(a0p)); sA.y = sqrtf(sigm(a0n));
    sA.z = sqrtf(sigm(b0p)); sA.w = sqrtf(sigm(b0n));
    cb[1 + j] = sA;
    if (j < 62) {
        float4 sB;
        sB.x = sqrtf(sigm(a1p)); sB.y = sqrtf(sigm(a1n));
        sB.z = sqrtf(sigm(b1p)); sB.w = sqrtf(sigm(b1n));
        cb[65 + j] = sB;
    }

    // D = sigmoid(diff) * know  (know in {0,1} -> exact)
    float dv0 = sigm(d0) * k0, dv1 = sigm(d1) * k1;
    u16 h0 = f2bf_rn(dv0), h1 = f2bf_rn(dv1);
    dhi[(size_t)row * NKNOW + j]      = h0;
    dhi[(size_t)row * NKNOW + 64 + j] = h1;
    dlo[(size_t)row * NKNOW + j]      = f2bf_rn(dv0 - bf2f(h0));
    dlo[(size_t)row * NKNOW + 64 + j] = f2bf_rn(dv1 - bf2f(h1));

    // know bitmask + header
    u64 m0 = __ballot(k0 > 0.5f);
    u64 m1 = __ballot(k1 > 0.5f);
    if (j == 0) {
        float4 h; h.x = sigm(c0p); h.y = sigm(c0n); h.z = sigm(pri); h.w = 0.f;
        cb[0] = h;
        uint4 mm; mm.x = (u32)m0; mm.y = (u32)(m0 >> 32);
        mm.z = (u32)m1; mm.w = (u32)(m1 >> 32);
        *(uint4*)(cb + 127) = mm;
    }
}

// ======================= K2: chain (one row per lane) ======================
__global__ __launch_bounds__(64) void chain_ncd(
    const float4* __restrict__ chainbuf,
    u32* __restrict__ mhi32,
    u32* __restrict__ mlo32)
{
    const int row = blockIdx.x * 64 + threadIdx.x;
    const float4* cb = chainbuf + (size_t)row * 128;
    float4 h = cb[0];
    uint4  mm = *(const uint4*)(cb + 127);
    const u64 b0 = (u64)mm.x | ((u64)mm.y << 32);
    const u64 b1 = (u64)mm.z | ((u64)mm.w << 32);
    u32* mh = mhi32 + (size_t)row * 64;
    u32* ml = mlo32 + (size_t)row * 64;

    float p0 = h.z;
    float p1 = fmaf(p0, h.x - h.y, h.y);
    {
        float v0 = (b0 & 1ull) ? p0 : 0.f;
        float v1 = (b0 & 2ull) ? p1 : 0.f;
        u16 q0 = f2bf_rn(v0), q1 = f2bf_rn(v1);
        mh[0] = (u32)q0 | ((u32)q1 << 16);
        ml[0] = (u32)f2bf_rn(v0 - bf2f(q0)) | ((u32)f2bf_rn(v1 - bf2f(q1)) << 16);
    }

    float pm2 = p0, pm1 = p1, pendm = 0.f;
    float4 A[14], Bv[14];

#define LOADB(buf, bi)                                            \
    _Pragma("unroll")                                             \
    for (int t = 0; t < 14; ++t) buf[t] = cb[1 + 14 * (bi) + t];

#define STEPS(buf, bi)                                            \
    _Pragma("unroll")                                             \
    for (int t = 0; t < 14; ++t) {                                \
        const int k = 2 + 14 * (bi) + t;                          \
        float4 s = buf[t];                                        \
        float ta = fmaf(pm2, s.x - s.y, s.y);                     \
        float tb = fmaf(pm1, s.z - s.w, s.w);                     \
        float pk = ta * tb;                                       \
        bool bit = (k < 64) ? ((b0 >> k) & 1ull) : ((b1 >> (k - 64)) & 1ull); \
        float pkm = bit ? pk : 0.f;                               \
        if (k & 1) {                                              \
            u16 q0 = f2bf_rn(pendm), q1 = f2bf_rn(pkm);           \
            mh[k >> 1] = (u32)q0 | ((u32)q1 << 16);               \
            ml[k >> 1] = (u32)f2bf_rn(pendm - bf2f(q0)) |         \
                         ((u32)f2bf_rn(pkm - bf2f(q1)) << 16);    \
        } else pendm = pkm;                                       \
        pm2 = pm1; pm1 = pk;                                      \
    }

    LOADB(A, 0);
    LOADB(Bv, 1); STEPS(A, 0);
    LOADB(A, 2);  STEPS(Bv, 1);
    LOADB(Bv, 3); STEPS(A, 2);
    LOADB(A, 4);  STEPS(Bv, 3);
    LOADB(Bv, 5); STEPS(A, 4);
    LOADB(A, 6);  STEPS(Bv, 5);
    LOADB(Bv, 7); STEPS(A, 6);
    LOADB(A, 8);  STEPS(Bv, 7);
    STEPS(A, 8);
#undef LOADB
#undef STEPS
}

// ======================= K3: gemm (proven R3 version) ======================
__global__ __launch_bounds__(256, 2) void gemm_ncd(
    const int*   __restrict__ item_ids,
    const float* __restrict__ item_disc_w,
    const float* __restrict__ bu,
    const float* __restrict__ bi,
    const u16*   __restrict__ wsp,
    const u32*   __restrict__ mhi32,
    const u32*   __restrict__ mlo32,
    const u32*   __restrict__ dhi32,
    const u32*   __restrict__ dlo32,
    float*       __restrict__ out)
{
    __shared__ float sRed[4][RPB3];

    const int tid  = threadIdx.x;
    const int lane = tid & 63;
    const int wid  = tid >> 6;
    const int l15  = lane & 15, lq = lane >> 4;
    const int r0   = blockIdx.x * RPB3;

    const u16* WuH = wsp;
    const u16* WuL = wsp + 32768;
    const u16* WiH = wsp + 65536;
    const u16* WiL = wsp + 98304;

    float rowsum[2][4] = {{0.f,0.f,0.f,0.f},{0.f,0.f,0.f,0.f}};

    #pragma unroll 1
    for (int t = 0; t < 4; ++t) {
        const int hcol = wid * 64 + t * 16 + l15;
        s16x8 uh[4], ul[4], ih[4], il[4];
        #pragma unroll
        for (int kc = 0; kc < 4; ++kc) {
            const int ke = kc * 32 + lq * 8;
            uh[kc] = *(const s16x8*)(WuH + hcol * NKNOW + ke);
            ul[kc] = *(const s16x8*)(WuL + hcol * NKNOW + ke);
            ih[kc] = *(const s16x8*)(WiH + hcol * NKNOW + ke);
            il[kc] = *(const s16x8*)(WiL + hcol * NKNOW + ke);
        }
        const float bub = bu[hcol], bib = bi[hcol];

        #pragma unroll
        for (int rg = 0; rg < 2; ++rg) {
            const int row = r0 + rg * 16 + l15;
            f32x4 accU = {0.f, 0.f, 0.f, 0.f};
            f32x4 accV = {0.f, 0.f, 0.f, 0.f};
            #pragma unroll
            for (int kc = 0; kc < 4; ++kc) {
                const int aoff = row * 64 + kc * 16 + lq * 4;
                s16x8 mh = *(const s16x8*)(mhi32 + aoff);
                s16x8 mlv = *(const s16x8*)(mlo32 + aoff);
                s16x8 dh = *(const s16x8*)(dhi32 + aoff);
                s16x8 dl = *(const s16x8*)(dlo32 + aoff);
                accU = __builtin_amdgcn_mfma_f32_16x16x32_bf16(mh, uh[kc], accU, 0, 0, 0);
                accU = __builtin_amdgcn_mfma_f32_16x16x32_bf16(mh, ul[kc], accU, 0, 0, 0);
                accU = __builtin_amdgcn_mfma_f32_16x16x32_bf16(mlv, uh[kc], accU, 0, 0, 0);
                accV = __builtin_amdgcn_mfma_f32_16x16x32_bf16(dh, ih[kc], accV, 0, 0, 0);
                accV = __builtin_amdgcn_mfma_f32_16x16x32_bf16(dh, il[kc], accV, 0, 0, 0);
                accV = __builtin_amdgcn_mfma_f32_16x16x32_bf16(dl, ih[kc], accV, 0, 0, 0);
            }
            #pragma unroll
            for (int j = 0; j < 4; ++j) {
                float x = accU[j] + bub;
                float u = 1.0f - 2.0f / (1.0f + __expf(2.0f * x));   // tanh
                float v = sigm(accV[j] + bib);
                rowsum[rg][j] += u * v;
            }
        }
    }

    #pragma unroll
    for (int rg = 0; rg < 2; ++rg)
        #pragma unroll
        for (int j = 0; j < 4; ++j) {
            float v = rowsum[rg][j];
            v += __shfl_xor(v, 1);
            v += __shfl_xor(v, 2);
            v += __shfl_xor(v, 4);
            v += __shfl_xor(v, 8);
            if (l15 == 0) sRed[wid][rg * 16 + lq * 4 + j] = v;
        }
    __syncthreads();

    if (tid < RPB3) {
        const int row = r0 + tid;
        float s = sRed[0][tid] + sRed[1][tid] + sRed[2][tid] + sRed[3][tid];
        float disc = sigm(item_disc_w[item_ids[row]]);
        out[row] = sigm(s - disc);
    }
}

// ======================= Fallback: R1 fused kernel =========================
__device__ __forceinline__ int swz(int row, int kbyte) {
    return row * 256 + (kbyte ^ ((row & 7) << 4));
}
__device__ __forceinline__ void store_pair(char* Mh, char* Ml, int r, int k0, float va, float vb) {
    int off = swz(r, k0 * 2);
    u16 ha = f2bf_rn(va); u16 la = f2bf_rn(va - bf2f(ha));
    u16 hb = f2bf_rn(vb); u16 lb = f2bf_rn(vb - bf2f(hb));
    *(u32*)(Mh + off) = (u32)ha | ((u32)hb << 16);
    *(u32*)(Ml + off) = (u32)la | ((u32)lb << 16);
}

__global__ __launch_bounds__(256, 3) void fused_ncd(
    const int*   __restrict__ user_ids,
    const int*   __restrict__ item_ids,
    const float* __restrict__ item_know,
    const float* __restrict__ priori,
    const float* __restrict__ condi_p,
    const float* __restrict__ condi_n,
    const float* __restrict__ item_diff_w,
    const float* __restrict__ item_disc_w,
    const float* __restrict__ bu,
    const float* __restrict__ bi,
    const u16* __restrict__ wsp,
    float*       __restrict__ out)
{
    __shared__ float sPair[RPB][508];
    __shared__ __align__(16) u16 sMhi[RPB * 128];
    __shared__ __align__(16) u16 sMlo[RPB * 128];
    __shared__ __align__(16) u16 sDhi[RPB * 128];
    __shared__ __align__(16) u16 sDlo[RPB * 128];
    __shared__ __align__(16) u16 sKmF[RPB * 128];
    __shared__ float sRed[4][RPB];
    __shared__ float sDisc[RPB];

    const int tid  = threadIdx.x;
    const int lane = tid & 63;
    const int wid  = tid >> 6;
    const int r0   = blockIdx.x * RPB;

    for (int rr = 0; rr < 4; ++rr) {
        const int r   = wid * 4 + rr;
        const int row = r0 + r;
        const int uid = user_ids[row];
        const int iid = item_ids[row];
        const float* cp = condi_p + (size_t)uid * NEDGE;
        const float* cn = condi_n + (size_t)uid * NEDGE;
        for (int e = lane; e < NEDGE; e += 64) {
            float p = sigm(cp[e]);
            float n = sigm(cn[e]);
            if (e >= 1) { p = sqrtf(p); n = sqrtf(n); }
            *(float2*)&sPair[r][2 * e] = make_float2(p, n);
        }
        const float* dw = item_diff_w + (size_t)iid * NKNOW;
        const float* kw = item_know   + (size_t)row * NKNOW;
        for (int e = lane; e < NKNOW; e += 64) {
            float kv = kw[e];
            float dv = sigm(dw[e]) * kv;
            u16 dh = f2bf_rn(dv);
            u16 dl = f2bf_rn(dv - bf2f(dh));
            int off = swz(r, 2 * e);
            *(u16*)((char*)sDhi + off) = dh;
            *(u16*)((char*)sDlo + off) = dl;
            *(u16*)((char*)sKmF + off) = (kv > 0.5f) ? (u16)0xFFFFu : (u16)0;
        }
    }
    __syncthreads();

    if (tid < RPB) {
        const int r   = tid;
        const int row = r0 + r;
        const int uid = user_ids[row];
        const int iid = item_ids[row];
        const float* P = &sPair[r][0];
        float p0 = sigm(priori[(size_t)uid * NKNOW]);
        float2 c0 = *(const float2*)&P[0];
        float p1 = c0.x * p0 + c0.y * (1.0f - p0);
        store_pair((char*)sMhi, (char*)sMlo, r, 0, p0, p1);
        float pm2 = p0, pm1 = p1, pev = 0.0f;
        for (int k = 2; k < NKNOW; ++k) {
            float2 a = *(const float2*)&P[2 * (125 + k)];
            float2 b = *(const float2*)&P[2 * (k - 1)];
            float ta = fmaf(pm2, a.x - a.y, a.y);
            float tb = fmaf(pm1, b.x - b.y, b.y);
            float pk = ta * tb;
            if (k & 1) store_pair((char*)sMhi, (char*)sMlo, r, k - 1, pev, pk);
            else       pev = pk;
            pm2 = pm1; pm1 = pk;
        }
        sDisc[r] = sigm(item_disc_w[iid]);
    }
    __syncthreads();

    const int l15 = lane & 15, lq = lane >> 4;
    const u16* WuH = wsp;
    const u16* WuL = wsp + 32768;
    const u16* WiH = wsp + 65536;
    const u16* WiL = wsp + 98304;

    float rowsum[4] = {0.f, 0.f, 0.f, 0.f};

    for (int t = 0; t < 4; ++t) {
        const int hcol = wid * 64 + t * 16 + l15;
        f32x4 accU = {0.f, 0.f, 0.f, 0.f};
        f32x4 accV = {0.f, 0.f, 0.f, 0.f};
        const u16* wuh = WuH + hcol * NKNOW;
        const u16* wul = WuL + hcol * NKNOW;
        const u16* wih = WiH + hcol * NKNOW;
        const u16* wil = WiL + hcol * NKNOW;
        #pragma unroll
        for (int kc = 0; kc < 4; ++kc) {
            const int offA = swz(l15, kc * 64 + lq * 16);
            const int ke   = kc * 32 + lq * 8;
            i32x4 km = *(const i32x4*)((const char*)sKmF + offA);
            i32x4 mh = *(const i32x4*)((const char*)sMhi + offA) & km;
            i32x4 ml = *(const i32x4*)((const char*)sMlo + offA) & km;
            s16x8 ah = *(s16x8*)&mh;
            s16x8 al = *(s16x8*)&ml;
            s16x8 bh = *(const s16x8*)((const char*)sDhi + offA);
            s16x8 bl = *(const s16x8*)((const char*)sDlo + offA);
            s16x8 uh = *(const s16x8*)(wuh + ke);
            s16x8 ul = *(const s16x8*)(wul + ke);
            s16x8 ih = *(const s16x8*)(wih + ke);
            s16x8 il = *(const s16x8*)(wil + ke);
            accU = __builtin_amdgcn_mfma_f32_16x16x32_bf16(ah, uh, accU, 0, 0, 0);
            accU = __builtin_amdgcn_mfma_f32_16x16x32_bf16(ah, ul, accU, 0, 0, 0);
            accU = __builtin_amdgcn_mfma_f32_16x16x32_bf16(al, uh, accU, 0, 0, 0);
            accV = __builtin_amdgcn_mfma_f32_16x16x32_bf16(bh, ih, accV, 0, 0, 0);
            accV = __builtin_amdgcn_mfma_f32_16x16x32_bf16(bh, il, accV, 0, 0, 0);
            accV = __builtin_amdgcn_mfma_f32_16x16x32_bf16(bl, ih, accV, 0, 0, 0);
        }
        const float bub = bu[hcol], bib = bi[hcol];
        #pragma unroll
        for (int j = 0; j < 4; ++j) {
            float x = accU[j] + bub;
            float u = 1.0f - 2.0f / (1.0f + __expf(2.0f * x));
            float v = sigm(accV[j] + bib);
            rowsum[j] += u * v;
        }
    }

    #pragma unroll
    for (int j = 0; j < 4; ++j) {
        float v = rowsum[j];
        v += __shfl_xor(v, 1);
        v += __shfl_xor(v, 2);
        v += __shfl_xor(v, 4);
        v += __shfl_xor(v, 8);
        if (l15 == 0) sRed[wid][lq * 4 + j] = v;
    }
    __syncthreads();

    if (tid < RPB) {
        float logit = sRed[0][tid] + sRed[1][tid] + sRed[2][tid] + sRed[3][tid] - sDisc[tid];
        out[r0 + tid] = sigm(logit);
    }
}

extern "C" void kernel_launch(void* const* d_in, const int* in_sizes, int n_in,
                              void* d_out, int out_size, void* d_ws, size_t ws_size,
                              hipStream_t stream) {
    const int*   user_ids    = (const int*)  d_in[0];
    const int*   item_ids    = (const int*)  d_in[1];
    const float* item_know   = (const float*)d_in[2];
    const float* priori      = (const float*)d_in[3];
    const float* condi_p     = (const float*)d_in[4];
    const float* condi_n     = (const float*)d_in[5];
    const float* item_diff_w = (const float*)d_in[6];
    const float* item_disc_w = (const float*)d_in[7];
    const float* Wu          = (const float*)d_in[8];
    const float* bu          = (const float*)d_in[9];
    const float* Wi          = (const float*)d_in[10];
    const float* bi          = (const float*)d_in[11];
    float* out = (float*)d_out;

    char* base = (char*)d_ws;
    u16*    wsp      = (u16*)base;                                   // 256 KiB
    float4* chainbuf = (float4*)(base + 0x40000);                    // 32 MiB
    u32*    mhi32    = (u32*)(base + 0x40000 + 0x2000000);           // 4 MiB
    u32*    mlo32    = (u32*)(base + 0x40000 + 0x2400000);           // 4 MiB
    u16*    dhi      = (u16*)(base + 0x40000 + 0x2800000);           // 4 MiB
    u16*    dlo      = (u16*)(base + 0x40000 + 0x2C00000);           // 4 MiB
    const size_t need = 0x40000 + 0x3000000;

    conv_w<<<256, 256, 0, stream>>>(Wu, Wi, wsp);

    if (ws_size >= need) {
        gather_ncd<<<BATCH / 4, 256, 0, stream>>>(
            user_ids, item_ids, item_know, priori, condi_p, condi_n,
            item_diff_w, chainbuf, dhi, dlo);
        chain_ncd<<<BATCH / 64, 64, 0, stream>>>(chainbuf, mhi32, mlo32);
        gemm_ncd<<<BATCH / RPB3, 256, 0, stream>>>(
            item_ids, item_disc_w, bu, bi, wsp,
            mhi32, mlo32, (const u32*)dhi, (const u32*)dlo, out);
    } else {
        fused_ncd<<<BATCH / RPB, 256, 0, stream>>>(
            user_ids, item_ids, item_know, priori, condi_p, condi_n,
            item_diff_w, item_disc_w, bu, bi, wsp, out);
    }
}

// Round 8
// 49.692 us; speedup vs baseline: 2.2749x; 1.3195x over previous
//
#include <hip/hip_runtime.h>

#define BATCH   16384
#define NKNOW   128
#define NEDGE   253
#define RPB     16

typedef __attribute__((ext_vector_type(8))) short  s16x8;   // 8 bf16 MFMA operand
typedef __attribute__((ext_vector_type(4))) float  f32x4;   // MFMA accumulator
typedef __attribute__((ext_vector_type(4))) int    i32x4;

typedef unsigned short u16;
typedef unsigned int   u32;
typedef unsigned long long u64;

__device__ __forceinline__ float sigm(float x) { return 1.0f / (1.0f + __expf(-x)); }

__device__ __forceinline__ u16 f2bf_rn(float x) {
    u32 u = __float_as_uint(x);
    u += 0x7FFFu + ((u >> 16) & 1u);
    return (u16)(u >> 16);
}
__device__ __forceinline__ float bf2f(u16 h) { return __uint_as_float(((u32)h) << 16); }

// R1-proven LDS swizzle: row-major 256B rows, XOR bits 4-6 with row&7
__device__ __forceinline__ int swz(int row, int kbyte) {
    return row * 256 + (kbyte ^ ((row & 7) << 4));
}
__device__ __forceinline__ void store_pair(char* Mh, char* Ml, int r, int k0, float va, float vb) {
    int off = swz(r, k0 * 2);
    u16 ha = f2bf_rn(va); u16 la = f2bf_rn(va - bf2f(ha));
    u16 hb = f2bf_rn(vb); u16 lb = f2bf_rn(vb - bf2f(hb));
    *(u32*)(Mh + off) = (u32)ha | ((u32)hb << 16);
    *(u32*)(Ml + off) = (u32)la | ((u32)lb << 16);
}

// ======================= K1: gather (+ merged conv_w) ======================
// cbT[slot][row] (slot-major, BATCH stride):
//   slot 0      = header (sig cp0, sig cn0, sig priori0, 0)
//   slot 1..126 = step k=slot+1: (cpa,cna,cpb,cnb) sqrt'd sigmoids
__global__ __launch_bounds__(256, 4) void gather_ncd(
    const int*   __restrict__ user_ids,
    const float* __restrict__ priori,
    const float* __restrict__ condi_p,
    const float* __restrict__ condi_n,
    const float* __restrict__ Wu,
    const float* __restrict__ Wi,
    u16*         __restrict__ wsp,
    float4*      __restrict__ cbT)
{
    __shared__ float4 stage[4][128];        // [rr][slot], 8 KB

    const int wid = threadIdx.x >> 6, j = threadIdx.x & 63;
    const int r0  = blockIdx.x * 4;
    const int row = r0 + wid;
    const int uid = user_ids[row];
    const float* cp = condi_p + (size_t)uid * NEDGE;
    const float* cn = condi_n + (size_t)uid * NEDGE;

    // issue all independent loads up front
    float a0p = cp[127 + j], a0n = cn[127 + j], b0p = cp[1 + j], b0n = cn[1 + j];
    float a1p = 0.f, a1n = 0.f, b1p = 0.f, b1n = 0.f;
    if (j < 62) { a1p = cp[191 + j]; a1n = cn[191 + j]; b1p = cp[65 + j]; b1n = cn[65 + j]; }
    float c0p = cp[0], c0n = cn[0], pri = priori[(size_t)uid * NKNOW];

    float4 sA;
    sA.x = sqrtf(sigm(a0p)); sA.y = sqrtf(sigm(a0n));
    sA.z = sqrtf(sigm(b0p)); sA.w = sqrtf(sigm(b0n));
    stage[wid][1 + j] = sA;
    if (j < 62) {
        float4 sB;
        sB.x = sqrtf(sigm(a1p)); sB.y = sqrtf(sigm(a1n));
        sB.z = sqrtf(sigm(b1p)); sB.w = sqrtf(sigm(b1n));
        stage[wid][65 + j] = sB;
    }
    if (j == 0) {
        float4 h; h.x = sigm(c0p); h.y = sigm(c0n); h.z = sigm(pri); h.w = 0.f;
        stage[wid][0] = h;
    }
    __syncthreads();

    // transposed write-out: 127 slots x 4 rows, 64B-contiguous per slot
    for (int idx = threadIdx.x; idx < 4 * 127; idx += 256) {
        const int slot = idx >> 2, rr = idx & 3;
        cbT[(size_t)slot * BATCH + r0 + rr] = stage[rr][slot];
    }

    // merged conv_w: blocks 0..255 convert Wu/Wi fp32 -> bf16 hi/lo in wsp
    if (blockIdx.x < 256) {
        int i = blockIdx.x * 256 + threadIdx.x;          // 0..65535
        bool isU = i < 32768;
        int  jj  = isU ? i : i - 32768;
        float w  = isU ? Wu[jj] : Wi[jj];
        u16 h = f2bf_rn(w);
        u16 l = f2bf_rn(w - bf2f(h));
        int base = isU ? 0 : 65536;
        wsp[base + jj]         = h;
        wsp[base + 32768 + jj] = l;
    }
}

// ======================= K2: chain + D-prep + gemm (fused) =================
// 512 blocks x 256 thr, 32 rows/block.
// Phase A: wave0 lanes0-31 = 32 serial chains (coalesced cbT reads);
//          waves1-2 = know/diff gather -> sDh/sDl/sKm; wave3 = disc.
// Phase B: R1-proven MFMA gemm (mask-AND on A), 2 row-groups of 16.
__global__ __launch_bounds__(256, 2) void cg_ncd(
    const int*   __restrict__ item_ids,
    const float* __restrict__ item_know,
    const float* __restrict__ item_diff_w,
    const float* __restrict__ item_disc_w,
    const float* __restrict__ bu,
    const float* __restrict__ bi,
    const u16*   __restrict__ wsp,
    const float4* __restrict__ cbT,
    float*       __restrict__ out)
{
    __shared__ __align__(16) u16 sMh[32 * 128];
    __shared__ __align__(16) u16 sMl[32 * 128];
    __shared__ __align__(16) u16 sDh[32 * 128];
    __shared__ __align__(16) u16 sDl[32 * 128];
    __shared__ __align__(16) u16 sKm[32 * 128];
    __shared__ float sRed[4][32];
    __shared__ float sDisc[32];

    const int tid  = threadIdx.x;
    const int lane = tid & 63;
    const int wid  = tid >> 6;
    const int r0   = blockIdx.x * 32;

    if (wid == 0) {
        if (lane < 32) {
            const int r = lane;
            const float4* base = cbT + (r0 + r);
            float4 h = base[0];
            float p0 = h.z;
            float p1 = fmaf(p0, h.x - h.y, h.y);
            store_pair((char*)sMh, (char*)sMl, r, 0, p0, p1);

            float pm2 = p0, pm1 = p1, pev = 0.f;
            float4 A[14], Bv[14];
#define LOADB(buf, bi_)                                               \
    _Pragma("unroll")                                                 \
    for (int t = 0; t < 14; ++t)                                      \
        buf[t] = base[(size_t)(1 + 14 * (bi_) + t) * BATCH];
#define STEPS(buf, bi_)                                               \
    _Pragma("unroll")                                                 \
    for (int t = 0; t < 14; ++t) {                                    \
        const int k = 2 + 14 * (bi_) + t;                             \
        float4 s = buf[t];                                            \
        float ta = fmaf(pm2, s.x - s.y, s.y);                         \
        float tb = fmaf(pm1, s.z - s.w, s.w);                         \
        float pk = ta * tb;                                           \
        if (k & 1) store_pair((char*)sMh, (char*)sMl, r, k - 1, pev, pk); \
        else       pev = pk;                                          \
        pm2 = pm1; pm1 = pk;                                          \
    }
            LOADB(A, 0);
            LOADB(Bv, 1); STEPS(A, 0);
            LOADB(A, 2);  STEPS(Bv, 1);
            LOADB(Bv, 3); STEPS(A, 2);
            LOADB(A, 4);  STEPS(Bv, 3);
            LOADB(Bv, 5); STEPS(A, 4);
            LOADB(A, 6);  STEPS(Bv, 5);
            LOADB(Bv, 7); STEPS(A, 6);
            LOADB(A, 8);  STEPS(Bv, 7);
            STEPS(A, 8);
#undef LOADB
#undef STEPS
        }
    } else if (wid <= 2) {
        const int rbase = (wid - 1) * 16;
        for (int rr = 0; rr < 16; ++rr) {
            const int r = rbase + rr, row = r0 + r;
            const int iid = item_ids[row];
            const float* kw = item_know   + (size_t)row * NKNOW;
            const float* dw = item_diff_w + (size_t)iid * NKNOW;
            #pragma unroll
            for (int half = 0; half < 2; ++half) {
                const int e = half * 64 + lane;
                float kv = kw[e];
                float dv = sigm(dw[e]) * kv;              // know in {0,1} -> exact
                u16 dh = f2bf_rn(dv);
                u16 dl = f2bf_rn(dv - bf2f(dh));
                const int off = swz(r, 2 * e);
                *(u16*)((char*)sDh + off) = dh;
                *(u16*)((char*)sDl + off) = dl;
                *(u16*)((char*)sKm + off) = (kv > 0.5f) ? (u16)0xFFFFu : (u16)0;
            }
        }
    } else {
        if (lane < 32) sDisc[lane] = sigm(item_disc_w[item_ids[r0 + lane]]);
    }
    __syncthreads();

    // ---------------- Phase B: MFMA gemm (R1/R3-proven) -------------------
    const int l15 = lane & 15, lq = lane >> 4;
    const u16* WuH = wsp;
    const u16* WuL = wsp + 32768;
    const u16* WiH = wsp + 65536;
    const u16* WiL = wsp + 98304;

    float rowsum[2][4] = {{0.f,0.f,0.f,0.f},{0.f,0.f,0.f,0.f}};

    #pragma unroll 1
    for (int t = 0; t < 4; ++t) {
        const int hcol = wid * 64 + t * 16 + l15;
        s16x8 uh[4], ul[4], ih[4], il[4];
        #pragma unroll
        for (int kc = 0; kc < 4; ++kc) {
            const int ke = kc * 32 + lq * 8;
            uh[kc] = *(const s16x8*)(WuH + hcol * NKNOW + ke);
            ul[kc] = *(const s16x8*)(WuL + hcol * NKNOW + ke);
            ih[kc] = *(const s16x8*)(WiH + hcol * NKNOW + ke);
            il[kc] = *(const s16x8*)(WiL + hcol * NKNOW + ke);
        }
        const float bub = bu[hcol], bib = bi[hcol];

        #pragma unroll
        for (int rg = 0; rg < 2; ++rg) {
            const int lr = rg * 16 + l15;                 // LDS row 0..31
            f32x4 accU = {0.f, 0.f, 0.f, 0.f};
            f32x4 accV = {0.f, 0.f, 0.f, 0.f};
            #pragma unroll
            for (int kc = 0; kc < 4; ++kc) {
                const int offA = swz(lr, kc * 64 + lq * 16);
                i32x4 km = *(const i32x4*)((const char*)sKm + offA);
                i32x4 mh = *(const i32x4*)((const char*)sMh + offA) & km;
                i32x4 ml = *(const i32x4*)((const char*)sMl + offA) & km;
                s16x8 ah = *(s16x8*)&mh;
                s16x8 al = *(s16x8*)&ml;
                s16x8 dh = *(const s16x8*)((const char*)sDh + offA);
                s16x8 dl = *(const s16x8*)((const char*)sDl + offA);
                accU = __builtin_amdgcn_mfma_f32_16x16x32_bf16(ah, uh[kc], accU, 0, 0, 0);
                accU = __builtin_amdgcn_mfma_f32_16x16x32_bf16(ah, ul[kc], accU, 0, 0, 0);
                accU = __builtin_amdgcn_mfma_f32_16x16x32_bf16(al, uh[kc], accU, 0, 0, 0);
                accV = __builtin_amdgcn_mfma_f32_16x16x32_bf16(dh, ih[kc], accV, 0, 0, 0);
                accV = __builtin_amdgcn_mfma_f32_16x16x32_bf16(dh, il[kc], accV, 0, 0, 0);
                accV = __builtin_amdgcn_mfma_f32_16x16x32_bf16(dl, ih[kc], accV, 0, 0, 0);
            }
            #pragma unroll
            for (int j = 0; j < 4; ++j) {                 // C/D: col=l15, row=lq*4+j
                float x = accU[j] + bub;
                float u = 1.0f - 2.0f / (1.0f + __expf(2.0f * x));   // tanh
                float v = sigm(accV[j] + bib);
                rowsum[rg][j] += u * v;
            }
        }
    }

    #pragma unroll
    for (int rg = 0; rg < 2; ++rg)
        #pragma unroll
        for (int j = 0; j < 4; ++j) {
            float v = rowsum[rg][j];
            v += __shfl_xor(v, 1);
            v += __shfl_xor(v, 2);
            v += __shfl_xor(v, 4);
            v += __shfl_xor(v, 8);
            if (l15 == 0) sRed[wid][rg * 16 + lq * 4 + j] = v;
        }
    __syncthreads();

    if (tid < 32) {
        float s = sRed[0][tid] + sRed[1][tid] + sRed[2][tid] + sRed[3][tid];
        out[r0 + tid] = sigm(s - sDisc[tid]);
    }
}

// ======================= Fallback: R1 fused kernel (proven) ================
__global__ void conv_w(const float* __restrict__ Wu, const float* __restrict__ Wi,
                       u16* __restrict__ wsp) {
    int i = blockIdx.x * 256 + threadIdx.x;
    bool isU = i < 32768;
    int  j   = isU ? i : i - 32768;
    float w  = isU ? Wu[j] : Wi[j];
    u16 h = f2bf_rn(w);
    u16 l = f2bf_rn(w - bf2f(h));
    int base = isU ? 0 : 65536;
    wsp[base + j]         = h;
    wsp[base + 32768 + j] = l;
}

__global__ __launch_bounds__(256, 3) void fused_ncd(
    const int*   __restrict__ user_ids,
    const int*   __restrict__ item_ids,
    const float* __restrict__ item_know,
    const float* __restrict__ priori,
    const float* __restrict__ condi_p,
    const float* __restrict__ condi_n,
    const float* __restrict__ item_diff_w,
    const float* __restrict__ item_disc_w,
    const float* __restrict__ bu,
    const float* __restrict__ bi,
    const u16* __restrict__ wsp,
    float*       __restrict__ out)
{
    __shared__ float sPair[RPB][508];
    __shared__ __align__(16) u16 sMhi[RPB * 128];
    __shared__ __align__(16) u16 sMlo[RPB * 128];
    __shared__ __align__(16) u16 sDhi[RPB * 128];
    __shared__ __align__(16) u16 sDlo[RPB * 128];
    __shared__ __align__(16) u16 sKmF[RPB * 128];
    __shared__ float sRed[4][RPB];
    __shared__ float sDisc[RPB];

    const int tid  = threadIdx.x;
    const int lane = tid & 63;
    const int wid  = tid >> 6;
    const int r0   = blockIdx.x * RPB;

    for (int rr = 0; rr < 4; ++rr) {
        const int r   = wid * 4 + rr;
        const int row = r0 + r;
        const int uid = user_ids[row];
        const int iid = item_ids[row];
        const float* cp = condi_p + (size_t)uid * NEDGE;
        const float* cn = condi_n + (size_t)uid * NEDGE;
        for (int e = lane; e < NEDGE; e += 64) {
            float p = sigm(cp[e]);
            float n = sigm(cn[e]);
            if (e >= 1) { p = sqrtf(p); n = sqrtf(n); }
            *(float2*)&sPair[r][2 * e] = make_float2(p, n);
        }
        const float* dw = item_diff_w + (size_t)iid * NKNOW;
        const float* kw = item_know   + (size_t)row * NKNOW;
        for (int e = lane; e < NKNOW; e += 64) {
            float kv = kw[e];
            float dv = sigm(dw[e]) * kv;
            u16 dh = f2bf_rn(dv);
            u16 dl = f2bf_rn(dv - bf2f(dh));
            int off = swz(r, 2 * e);
            *(u16*)((char*)sDhi + off) = dh;
            *(u16*)((char*)sDlo + off) = dl;
            *(u16*)((char*)sKmF + off) = (kv > 0.5f) ? (u16)0xFFFFu : (u16)0;
        }
    }
    __syncthreads();

    if (tid < RPB) {
        const int r   = tid;
        const int row = r0 + r;
        const int uid = user_ids[row];
        const int iid = item_ids[row];
        const float* P = &sPair[r][0];
        float p0 = sigm(priori[(size_t)uid * NKNOW]);
        float2 c0 = *(const float2*)&P[0];
        float p1 = c0.x * p0 + c0.y * (1.0f - p0);
        store_pair((char*)sMhi, (char*)sMlo, r, 0, p0, p1);
        float pm2 = p0, pm1 = p1, pev = 0.0f;
        for (int k = 2; k < NKNOW; ++k) {
            float2 a = *(const float2*)&P[2 * (125 + k)];
            float2 b = *(const float2*)&P[2 * (k - 1)];
            float ta = fmaf(pm2, a.x - a.y, a.y);
            float tb = fmaf(pm1, b.x - b.y, b.y);
            float pk = ta * tb;
            if (k & 1) store_pair((char*)sMhi, (char*)sMlo, r, k - 1, pev, pk);
            else       pev = pk;
            pm2 = pm1; pm1 = pk;
        }
        sDisc[r] = sigm(item_disc_w[iid]);
    }
    __syncthreads();

    const int l15 = lane & 15, lq = lane >> 4;
    const u16* WuH = wsp;
    const u16* WuL = wsp + 32768;
    const u16* WiH = wsp + 65536;
    const u16* WiL = wsp + 98304;

    float rowsum[4] = {0.f, 0.f, 0.f, 0.f};

    for (int t = 0; t < 4; ++t) {
        const int hcol = wid * 64 + t * 16 + l15;
        f32x4 accU = {0.f, 0.f, 0.f, 0.f};
        f32x4 accV = {0.f, 0.f, 0.f, 0.f};
        const u16* wuh = WuH + hcol * NKNOW;
        const u16* wul = WuL + hcol * NKNOW;
        const u16* wih = WiH + hcol * NKNOW;
        const u16* wil = WiL + hcol * NKNOW;
        #pragma unroll
        for (int kc = 0; kc < 4; ++kc) {
            const int offA = swz(l15, kc * 64 + lq * 16);
            const int ke   = kc * 32 + lq * 8;
            i32x4 km = *(const i32x4*)((const char*)sKmF + offA);
            i32x4 mh = *(const i32x4*)((const char*)sMhi + offA) & km;
            i32x4 ml = *(const i32x4*)((const char*)sMlo + offA) & km;
            s16x8 ah = *(s16x8*)&mh;
            s16x8 al = *(s16x8*)&ml;
            s16x8 bh = *(const s16x8*)((const char*)sDhi + offA);
            s16x8 bl = *(const s16x8*)((const char*)sDlo + offA);
            s16x8 uh = *(const s16x8*)(wuh + ke);
            s16x8 ul = *(const s16x8*)(wul + ke);
            s16x8 ih = *(const s16x8*)(wih + ke);
            s16x8 il = *(const s16x8*)(wil + ke);
            accU = __builtin_amdgcn_mfma_f32_16x16x32_bf16(ah, uh, accU, 0, 0, 0);
            accU = __builtin_amdgcn_mfma_f32_16x16x32_bf16(ah, ul, accU, 0, 0, 0);
            accU = __builtin_amdgcn_mfma_f32_16x16x32_bf16(al, uh, accU, 0, 0, 0);
            accV = __builtin_amdgcn_mfma_f32_16x16x32_bf16(bh, ih, accV, 0, 0, 0);
            accV = __builtin_amdgcn_mfma_f32_16x16x32_bf16(bh, il, accV, 0, 0, 0);
            accV = __builtin_amdgcn_mfma_f32_16x16x32_bf16(bl, ih, accV, 0, 0, 0);
        }
        const float bub = bu[hcol], bib = bi[hcol];
        #pragma unroll
        for (int j = 0; j < 4; ++j) {
            float x = accU[j] + bub;
            float u = 1.0f - 2.0f / (1.0f + __expf(2.0f * x));
            float v = sigm(accV[j] + bib);
            rowsum[j] += u * v;
        }
    }

    #pragma unroll
    for (int j = 0; j < 4; ++j) {
        float v = rowsum[j];
        v += __shfl_xor(v, 1);
        v += __shfl_xor(v, 2);
        v += __shfl_xor(v, 4);
        v += __shfl_xor(v, 8);
        if (l15 == 0) sRed[wid][lq * 4 + j] = v;
    }
    __syncthreads();

    if (tid < RPB) {
        float logit = sRed[0][tid] + sRed[1][tid] + sRed[2][tid] + sRed[3][tid] - sDisc[tid];
        out[r0 + tid] = sigm(logit);
    }
}

extern "C" void kernel_launch(void* const* d_in, const int* in_sizes, int n_in,
                              void* d_out, int out_size, void* d_ws, size_t ws_size,
                              hipStream_t stream) {
    const int*   user_ids    = (const int*)  d_in[0];
    const int*   item_ids    = (const int*)  d_in[1];
    const float* item_know   = (const float*)d_in[2];
    const float* priori      = (const float*)d_in[3];
    const float* condi_p     = (const float*)d_in[4];
    const float* condi_n     = (const float*)d_in[5];
    const float* item_diff_w = (const float*)d_in[6];
    const float* item_disc_w = (const float*)d_in[7];
    const float* Wu          = (const float*)d_in[8];
    const float* bu          = (const float*)d_in[9];
    const float* Wi          = (const float*)d_in[10];
    const float* bi          = (const float*)d_in[11];
    float* out = (float*)d_out;

    char* base = (char*)d_ws;
    u16*    wsp = (u16*)base;                                     // 256 KiB
    float4* cbT = (float4*)(base + 0x40000);                      // 127*BATCH*16 B
    const size_t need = 0x40000 + (size_t)127 * BATCH * 16;       // ~33.6 MiB

    if (ws_size >= need) {
        gather_ncd<<<BATCH / 4, 256, 0, stream>>>(
            user_ids, priori, condi_p, condi_n, Wu, Wi, wsp, cbT);
        cg_ncd<<<BATCH / 32, 256, 0, stream>>>(
            item_ids, item_know, item_diff_w, item_disc_w, bu, bi,
            wsp, cbT, out);
    } else {
        conv_w<<<256, 256, 0, stream>>>(Wu, Wi, wsp);
        fused_ncd<<<BATCH / RPB, 256, 0, stream>>>(
            user_ids, item_ids, item_know, priori, condi_p, condi_n,
            item_diff_w, item_disc_w, bu, bi, wsp, out);
    }
}